// Round 6
// baseline (575.486 us; speedup 1.0000x reference)
//
#include <hip/hip_runtime.h>
#include <hip/hip_bf16.h>

typedef unsigned short u16;
typedef float f32x4 __attribute__((ext_vector_type(4)));
typedef u16   u16x8 __attribute__((ext_vector_type(8)));
typedef u16   u16x4 __attribute__((ext_vector_type(4)));
typedef short s16x8 __attribute__((ext_vector_type(8)));

__device__ __forceinline__ u16 f2bf(float f) {
  unsigned u = __builtin_bit_cast(unsigned, f);
  unsigned r = (u + 0x7fffu + ((u >> 16) & 1u)) >> 16;
  return (u16)r;
}
__device__ __forceinline__ u16 cvtbf(float f) {
  return __builtin_bit_cast(u16, __float2bfloat16(f));
}

#define GL_LDS16(gp, lp)                                                     \
  __builtin_amdgcn_global_load_lds((const __attribute__((address_space(1))) void*)(gp), \
                                   (__attribute__((address_space(3))) void*)(lp), 16, 0, 0)

// ================= B = A * A^T (fp32, 64x64 tiles) =================
__global__ __launch_bounds__(256) void k_bbt(const float* __restrict__ A, float* __restrict__ B) {
  __shared__ float s0[32][68];
  __shared__ float s1[32][68];
  const int tid = threadIdx.x;
  const int i0 = blockIdx.y * 64, j0 = blockIdx.x * 64;
  const int tx = tid & 15, ty = tid >> 4;
  const int sr = tid >> 2, sc = (tid & 3) * 8;
  f32x4 acc[4];
#pragma unroll
  for (int q = 0; q < 4; ++q) acc[q] = {0.f, 0.f, 0.f, 0.f};

  for (int k0 = 0; k0 < 1024; k0 += 32) {
    f32x4 a0 = *(const f32x4*)&A[(size_t)(i0 + sr) * 1024 + k0 + sc];
    f32x4 a1 = *(const f32x4*)&A[(size_t)(i0 + sr) * 1024 + k0 + sc + 4];
    f32x4 b0 = *(const f32x4*)&A[(size_t)(j0 + sr) * 1024 + k0 + sc];
    f32x4 b1 = *(const f32x4*)&A[(size_t)(j0 + sr) * 1024 + k0 + sc + 4];
    __syncthreads();
#pragma unroll
    for (int q = 0; q < 4; ++q) {
      s0[sc + q][sr] = a0[q]; s0[sc + 4 + q][sr] = a1[q];
      s1[sc + q][sr] = b0[q]; s1[sc + 4 + q][sr] = b1[q];
    }
    __syncthreads();
#pragma unroll
    for (int kk = 0; kk < 32; ++kk) {
      f32x4 av = *(const f32x4*)&s0[kk][ty * 4];
      f32x4 bv = *(const f32x4*)&s1[kk][tx * 4];
#pragma unroll
      for (int q = 0; q < 4; ++q) acc[q] += bv * av[q];
    }
  }
#pragma unroll
  for (int q = 0; q < 4; ++q)
    *(f32x4*)&B[(size_t)(i0 + ty * 4 + q) * 1024 + j0 + tx * 4] = acc[q];
}

// ================= diag-block inverses T_k -> M diagonal; blocks 16..19: rd2 =================
__global__ __launch_bounds__(256) void k_tinv(const float* __restrict__ B, float* __restrict__ M,
                                              float* __restrict__ rd2) {
  __shared__ float Ct[64][68];
  __shared__ float rdl[64];
  const int tid = threadIdx.x;
  const int bid = blockIdx.x;
  if (bid >= 16) {
    int i = (bid - 16) * 256 + tid;
    rd2[i] = 2.0f / B[(size_t)i * 1025];
    return;
  }
  const int k0 = bid * 64;
  if (tid < 64) rdl[tid] = 2.0f / B[(size_t)(k0 + tid) * 1025];
  __syncthreads();
  {
    const int i = tid >> 2, j0q = (tid & 3) * 16;
#pragma unroll
    for (int jj = 0; jj < 16; ++jj) {
      int j = j0q + jj;
      Ct[i][j] = (j > i) ? B[(size_t)(k0 + i) * 1024 + k0 + j] * rdl[j] : 0.0f;
    }
  }
  __syncthreads();
  if (tid < 64) {
    float pc[64];
#pragma unroll
    for (int r = 0; r < 64; ++r) pc[r] = (r == tid) ? 1.0f : 0.0f;
#pragma unroll
    for (int i = 0; i < 63; ++i) {
      const float pi = pc[i];
#pragma unroll
      for (int j = i + 1; j < 64; ++j) pc[j] -= Ct[i][j] * pi;
    }
#pragma unroll
    for (int r = 0; r < 64; ++r) M[(size_t)(k0 + r) * 1024 + k0 + tid] = pc[r];
  }
}

// ================= level GEMM 1: U_p = Cscaled[a+s:a+2s, a:a+s] * M[a:a+s, a:a+s] =================
__global__ __launch_bounds__(256) void k_u(const float* __restrict__ B, const float* __restrict__ rd2,
                                           const float* __restrict__ M, float* __restrict__ U, int lvl) {
  __shared__ float sA[32][68];
  __shared__ float sB[32][68];
  const int tid = threadIdx.x;
  const int s = 64 << lvl;
  const int ti = blockIdx.x >> lvl, tj = blockIdx.x & ((1 << lvl) - 1);
  const int a = blockIdx.y * (s << 1);
  const int m0 = a + s + ti * 64;
  const int n0 = a + tj * 64;
  const int tx = tid & 15, ty = tid >> 4;
  const int asr = tid >> 2, asc = (tid & 3) * 8;
  const int bkr = tid >> 3, bnc = (tid & 7) * 8;
  const float r2 = rd2[m0 + asr];
  f32x4 acc[4];
#pragma unroll
  for (int q = 0; q < 4; ++q) acc[q] = {0.f, 0.f, 0.f, 0.f};

  for (int k0 = 0; k0 < s; k0 += 32) {
    f32x4 a0 = *(const f32x4*)&B[(size_t)(m0 + asr) * 1024 + a + k0 + asc];
    f32x4 a1 = *(const f32x4*)&B[(size_t)(m0 + asr) * 1024 + a + k0 + asc + 4];
    f32x4 b0 = *(const f32x4*)&M[(size_t)(a + k0 + bkr) * 1024 + n0 + bnc];
    f32x4 b1 = *(const f32x4*)&M[(size_t)(a + k0 + bkr) * 1024 + n0 + bnc + 4];
    a0 *= r2; a1 *= r2;
    __syncthreads();
#pragma unroll
    for (int q = 0; q < 4; ++q) { sA[asc + q][asr] = a0[q]; sA[asc + 4 + q][asr] = a1[q]; }
    *(f32x4*)&sB[bkr][bnc] = b0;
    *(f32x4*)&sB[bkr][bnc + 4] = b1;
    __syncthreads();
#pragma unroll
    for (int kk = 0; kk < 32; ++kk) {
      f32x4 av = *(const f32x4*)&sA[kk][ty * 4];
      f32x4 bv = *(const f32x4*)&sB[kk][tx * 4];
#pragma unroll
      for (int q = 0; q < 4; ++q) acc[q] += bv * av[q];
    }
  }
  float* up = U + (size_t)blockIdx.y * s * s;
#pragma unroll
  for (int q = 0; q < 4; ++q)
    *(f32x4*)&up[(size_t)(ti * 64 + ty * 4 + q) * s + tj * 64 + tx * 4] = acc[q];
}

// ================= level GEMM 2: M[a+s:a+2s, a:a+s] = - M[a+s:a+2s, a+s:a+2s] * U_p =================
__global__ __launch_bounds__(256) void k_moff(float* __restrict__ M, const float* __restrict__ U, int lvl) {
  __shared__ float sA[32][68];
  __shared__ float sB[32][68];
  const int tid = threadIdx.x;
  const int s = 64 << lvl;
  const int ti = blockIdx.x >> lvl, tj = blockIdx.x & ((1 << lvl) - 1);
  const int a = blockIdx.y * (s << 1);
  const int m0 = a + s + ti * 64;
  const int n0 = a + tj * 64;
  const int tx = tid & 15, ty = tid >> 4;
  const int asr = tid >> 2, asc = (tid & 3) * 8;
  const int bkr = tid >> 3, bnc = (tid & 7) * 8;
  const float* up = U + (size_t)blockIdx.y * s * s;
  f32x4 acc[4];
#pragma unroll
  for (int q = 0; q < 4; ++q) acc[q] = {0.f, 0.f, 0.f, 0.f};

  for (int k0 = 0; k0 < s; k0 += 32) {
    f32x4 a0 = *(const f32x4*)&M[(size_t)(m0 + asr) * 1024 + a + s + k0 + asc];
    f32x4 a1 = *(const f32x4*)&M[(size_t)(m0 + asr) * 1024 + a + s + k0 + asc + 4];
    f32x4 b0 = *(const f32x4*)&up[(size_t)(k0 + bkr) * s + tj * 64 + bnc];
    f32x4 b1 = *(const f32x4*)&up[(size_t)(k0 + bkr) * s + tj * 64 + bnc + 4];
    __syncthreads();
#pragma unroll
    for (int q = 0; q < 4; ++q) { sA[asc + q][asr] = a0[q]; sA[asc + 4 + q][asr] = a1[q]; }
    *(f32x4*)&sB[bkr][bnc] = b0;
    *(f32x4*)&sB[bkr][bnc + 4] = b1;
    __syncthreads();
#pragma unroll
    for (int kk = 0; kk < 32; ++kk) {
      f32x4 av = *(const f32x4*)&sA[kk][ty * 4];
      f32x4 bv = *(const f32x4*)&sB[kk][tx * 4];
#pragma unroll
      for (int q = 0; q < 4; ++q) acc[q] += bv * av[q];
    }
  }
#pragma unroll
  for (int q = 0; q < 4; ++q)
    *(f32x4*)&M[(size_t)(m0 + ty * 4 + q) * 1024 + n0 + tx * 4] = -acc[q];
}

// ================= Y = M * A (triangular K-skip) =================
__global__ __launch_bounds__(256) void k_yma(const float* __restrict__ M, const float* __restrict__ A,
                                             float* __restrict__ Y) {
  __shared__ float sA[32][68];
  __shared__ float sB[32][68];
  const int tid = threadIdx.x;
  const int ri = blockIdx.y, cj = blockIdx.x;
  const int m0 = ri * 64, n0 = cj * 64;
  const int kmax = (ri + 1) * 64;
  const int tx = tid & 15, ty = tid >> 4;
  const int asr = tid >> 2, asc = (tid & 3) * 8;
  const int bkr = tid >> 3, bnc = (tid & 7) * 8;
  f32x4 acc[4];
#pragma unroll
  for (int q = 0; q < 4; ++q) acc[q] = {0.f, 0.f, 0.f, 0.f};

  for (int k0 = 0; k0 < kmax; k0 += 32) {
    f32x4 a0 = *(const f32x4*)&M[(size_t)(m0 + asr) * 1024 + k0 + asc];
    f32x4 a1 = *(const f32x4*)&M[(size_t)(m0 + asr) * 1024 + k0 + asc + 4];
    f32x4 b0 = *(const f32x4*)&A[(size_t)(k0 + bkr) * 1024 + n0 + bnc];
    f32x4 b1 = *(const f32x4*)&A[(size_t)(k0 + bkr) * 1024 + n0 + bnc + 4];
    __syncthreads();
#pragma unroll
    for (int q = 0; q < 4; ++q) { sA[asc + q][asr] = a0[q]; sA[asc + 4 + q][asr] = a1[q]; }
    *(f32x4*)&sB[bkr][bnc] = b0;
    *(f32x4*)&sB[bkr][bnc + 4] = b1;
    __syncthreads();
#pragma unroll
    for (int kk = 0; kk < 32; ++kk) {
      f32x4 av = *(const f32x4*)&sA[kk][ty * 4];
      f32x4 bv = *(const f32x4*)&sB[kk][tx * 4];
#pragma unroll
      for (int q = 0; q < 4; ++q) acc[q] += bv * av[q];
    }
  }
#pragma unroll
  for (int q = 0; q < 4; ++q)
    *(f32x4*)&Y[(size_t)(m0 + ty * 4 + q) * 1024 + n0 + tx * 4] = acc[q];
}

// ================= Wf in MFMA-B-fragment order =================
__global__ __launch_bounds__(256) void k_w(const float* __restrict__ A, const float* __restrict__ P,
                                           const float* __restrict__ rd2, u16* __restrict__ Wf) {
  __shared__ float As[32][68];
  __shared__ float Ps[32][68];
  const int tid = threadIdx.x;
  const int kb = blockIdx.y * 64, nb = blockIdx.x * 64;
  const int sr = tid >> 3, sc = (tid & 7) * 8;
  const int tx = tid & 15, ty = tid >> 4;
  f32x4 acc[4];
#pragma unroll
  for (int q = 0; q < 4; ++q) acc[q] = {0.f, 0.f, 0.f, 0.f};

  for (int i0 = 0; i0 < 1024; i0 += 32) {
    float r2 = rd2[i0 + sr];
    f32x4 a0 = *(const f32x4*)&A[(size_t)(i0 + sr) * 1024 + kb + sc];
    f32x4 a1 = *(const f32x4*)&A[(size_t)(i0 + sr) * 1024 + kb + sc + 4];
    f32x4 p0 = *(const f32x4*)&P[(size_t)(i0 + sr) * 1024 + nb + sc];
    f32x4 p1 = *(const f32x4*)&P[(size_t)(i0 + sr) * 1024 + nb + sc + 4];
    __syncthreads();
    *(f32x4*)&As[sr][sc]     = a0 * r2;
    *(f32x4*)&As[sr][sc + 4] = a1 * r2;
    *(f32x4*)&Ps[sr][sc]     = p0;
    *(f32x4*)&Ps[sr][sc + 4] = p1;
    __syncthreads();
#pragma unroll
    for (int i = 0; i < 32; ++i) {
      f32x4 av = *(const f32x4*)&As[i][ty * 4];
      f32x4 pv = *(const f32x4*)&Ps[i][tx * 4];
#pragma unroll
      for (int q = 0; q < 4; ++q) acc[q] += pv * av[q];
    }
  }
  const int ktile = (kb + ty * 4) >> 5;
  const int kg = ((ty * 4) >> 3) & 3;
  const int e0 = (ty * 4) & 7;
#pragma unroll
  for (int j = 0; j < 4; ++j) {
    int n = nb + tx * 4 + j;
    int nt = n >> 4;
    int ln = kg * 16 + (n & 15);
    u16x4 pk;
#pragma unroll
    for (int q = 0; q < 4; ++q) {
      int kk = kb + ty * 4 + q;
      float w = ((kk == n) ? 1.0f : 0.0f) - acc[q][j];
      pk[q] = f2bf(w);
    }
    *(u16x4*)&Wf[((size_t)(ktile * 64 + nt) * 64 + ln) * 8 + e0] = pk;
  }
}

// ================= X fp32 -> bf16, A-fragment order for 256-row M-tiles =================
// layout: [mi256][it(16)][kt2(2)][msub(16)][lane(64)][8]
__global__ __launch_bounds__(256) void k_xbf(const float* __restrict__ X, u16* __restrict__ Xbf) {
  for (int gid = blockIdx.x * 256 + threadIdx.x; gid < (1 << 23); gid += gridDim.x * 256) {
    const int mi   = gid >> 15;
    const int it   = (gid >> 11) & 15;
    const int kt2  = (gid >> 10) & 1;
    const int msub = (gid >> 6) & 15;
    const int lane = gid & 63;
    const int m = mi * 256 + msub * 16 + (lane & 15);
    const int k = it * 64 + kt2 * 32 + (lane >> 4) * 8;
    const float* s = X + (size_t)m * 1024 + k;
    f32x4 u = *(const f32x4*)s;
    f32x4 v = *(const f32x4*)(s + 4);
    u16x8 h;
    h[0] = cvtbf(u[0]); h[1] = cvtbf(u[1]); h[2] = cvtbf(u[2]); h[3] = cvtbf(u[3]);
    h[4] = cvtbf(v[0]); h[5] = cvtbf(v[1]); h[6] = cvtbf(v[2]); h[7] = cvtbf(v[3]);
    *(u16x8*)(Xbf + (size_t)gid * 8) = h;
  }
}

// ================= 256x256 GEMM, counted-vmcnt half-tile pipeline =================
// 8 waves (2M x 4N). In-flight unit = BK=32 half (16KB A + 16KB B = 4 loads).
// 4 LDS slots (128 KiB total), depth-3 prefetch, vmcnt(8) steady state (never 0 mid-loop).
template<int I>
__device__ __forceinline__ void phase_body(const u16* __restrict__ ax, const u16* __restrict__ wbase,
                                           u16* As, u16* Bs, int tid, int wr, int wc, int lane,
                                           f32x4 (&acc)[8][4]) {
  // half I landed when <= (#loads of halves newer than I) outstanding; loads retire in order.
  if constexpr (I <= 29)      asm volatile("s_waitcnt vmcnt(8)" ::: "memory");
  else if constexpr (I == 30) asm volatile("s_waitcnt vmcnt(4)" ::: "memory");
  else                        asm volatile("s_waitcnt vmcnt(0)" ::: "memory");
  __builtin_amdgcn_s_barrier();   // all waves' half-I loads landed; slot (I+3)&3 reads finished
  if constexpr (I + 3 < 32) {
    constexpr int j = I + 3, jt = j >> 1, jk = j & 1, js = j & 3;
    GL_LDS16(ax + (size_t)jt * 16384 + jk * 8192 + tid * 8,            As + js * 8192 + tid * 8);
    GL_LDS16(ax + (size_t)jt * 16384 + jk * 8192 + 4096 + tid * 8,     As + js * 8192 + 4096 + tid * 8);
    GL_LDS16(wbase + (size_t)jt * 65536 + jk * 32768 + tid * 8,        Bs + js * 8192 + tid * 8);
    GL_LDS16(wbase + (size_t)jt * 65536 + jk * 32768 + 4096 + tid * 8, Bs + js * 8192 + 4096 + tid * 8);
  }
  const u16* Asb = As + (I & 3) * 8192;
  const u16* Bsb = Bs + (I & 3) * 8192;
  s16x8 af[8], bfr[4];
#pragma unroll
  for (int m = 0; m < 8; ++m) af[m] = *(const s16x8*)&Asb[(size_t)(wr * 8 + m) * 512 + lane * 8];
#pragma unroll
  for (int n = 0; n < 4; ++n) bfr[n] = *(const s16x8*)&Bsb[(size_t)(wc * 4 + n) * 512 + lane * 8];
  __builtin_amdgcn_s_setprio(1);
#pragma unroll
  for (int m = 0; m < 8; ++m)
#pragma unroll
    for (int n = 0; n < 4; ++n)
      acc[m][n] = __builtin_amdgcn_mfma_f32_16x16x32_bf16(af[m], bfr[n], acc[m][n], 0, 0, 0);
  __builtin_amdgcn_s_setprio(0);
}

__global__ __launch_bounds__(512, 2) void k_out8(const u16* __restrict__ Xbf, const u16* __restrict__ Wf,
                                                 const float* __restrict__ bvec, float* __restrict__ out) {
  __shared__ u16 As[32768];   // 4 slots x [msub(16)][lane(64)][8]  (64 KiB)
  __shared__ u16 Bs[32768];   // 4 slots x [nsub(16)][lane(64)][8]  (64 KiB)
  const int tid = threadIdx.x;
  const int lane = tid & 63, wid = tid >> 6;
  const int wr = wid >> 2, wc = wid & 3;          // 2M x 4N waves; per-wave out 128x64
  const int lin = blockIdx.x;
  const int xcd = lin & 7, idx = lin >> 3;
  const int mi = xcd * 32 + (idx >> 2);           // XCD-chunked
  const int ni = idx & 3;

  const u16* ax = Xbf + (size_t)mi * 262144;
  const u16* wbase = Wf + (size_t)ni * 8192;

  f32x4 acc[8][4];
#pragma unroll
  for (int m = 0; m < 8; ++m)
#pragma unroll
    for (int n = 0; n < 4; ++n) acc[m][n] = {0.f, 0.f, 0.f, 0.f};

  // prologue: issue halves 0,1,2 (12 loads)
#pragma unroll
  for (int j = 0; j < 3; ++j) {
    const int jt = j >> 1, jk = j & 1;
    GL_LDS16(ax + (size_t)jt * 16384 + jk * 8192 + tid * 8,            As + j * 8192 + tid * 8);
    GL_LDS16(ax + (size_t)jt * 16384 + jk * 8192 + 4096 + tid * 8,     As + j * 8192 + 4096 + tid * 8);
    GL_LDS16(wbase + (size_t)jt * 65536 + jk * 32768 + tid * 8,        Bs + j * 8192 + tid * 8);
    GL_LDS16(wbase + (size_t)jt * 65536 + jk * 32768 + 4096 + tid * 8, Bs + j * 8192 + 4096 + tid * 8);
  }

#define PH(I) phase_body<I>(ax, wbase, As, Bs, tid, wr, wc, lane, acc);
  PH(0)  PH(1)  PH(2)  PH(3)  PH(4)  PH(5)  PH(6)  PH(7)
  PH(8)  PH(9)  PH(10) PH(11) PH(12) PH(13) PH(14) PH(15)
  PH(16) PH(17) PH(18) PH(19) PH(20) PH(21) PH(22) PH(23)
  PH(24) PH(25) PH(26) PH(27) PH(28) PH(29) PH(30) PH(31)
#undef PH

  const long orow0 = (long)mi * 256 + wr * 128 + (lane >> 4) * 4;
  const int  ocol0 = ni * 256 + wc * 64 + (lane & 15);
#pragma unroll
  for (int aj = 0; aj < 4; ++aj) {
    const int cc = ocol0 + aj * 16;
    const float bb = bvec[cc];
#pragma unroll
    for (int ai = 0; ai < 8; ++ai) {
      const long r = orow0 + ai * 16;
#pragma unroll
      for (int q = 0; q < 4; ++q)
        out[(r + q) * 1024 + cc] = acc[ai][aj][q] + bb;
    }
  }
}

// ================= fallback GEMM (reg-staged A) if workspace too small for Xbf =================
__global__ __launch_bounds__(256) void k_out_r(const float* __restrict__ X, const u16* __restrict__ Wf,
                                               const float* __restrict__ bvec, float* __restrict__ out) {
  __shared__ u16 As[8192];
  __shared__ u16 Bs[8192];
  const int tid = threadIdx.x;
  const int lane = tid & 63, wid = tid >> 6;
  const int wr = wid >> 1, wc = wid & 1;
  const int lin = blockIdx.x;
  const int mi = (lin & 7) * 64 + (lin >> 6);
  const int ni = (lin >> 3) & 7;
  const long m0 = (long)mi * 128;
  const int n0 = ni * 128;

  const float *xs0, *xs1, *xs2, *xs3;
  int aw0, aw1, aw2, aw3;
#define APREP(J, XS, AW) { int c = (J) * 256 + tid; int m = c >> 3, kg8 = c & 7;       \
    XS = X + (m0 + m) * 1024 + kg8 * 8;                                                \
    int kt2 = kg8 >> 2, ks = kg8 & 3, msub = m >> 4, mm = m & 15;                      \
    AW = (((kt2 * 8 + msub) * 64 + ks * 16 + mm) * 16) ^ (ks << 4); }
  APREP(0, xs0, aw0) APREP(1, xs1, aw1) APREP(2, xs2, aw2) APREP(3, xs3, aw3)
#undef APREP

  const u16* wsrc0 = Wf + (size_t)ni * 4096 + tid * 8;
  u16* bd0 = Bs + tid * 8;
  const int aro = (lane * 16) ^ (((lane >> 4) & 3) << 4);
  const char* Ab = (const char*)As + aro;
  const char* Bb = (const char*)Bs + lane * 16;

  f32x4 acc[4][4];
#pragma unroll
  for (int m = 0; m < 4; ++m)
#pragma unroll
    for (int n = 0; n < 4; ++n) acc[m][n] = {0.f, 0.f, 0.f, 0.f};

  for (int it = 0; it < 16; ++it) {
    const u16* w0 = wsrc0 + (size_t)it * 65536;
    GL_LDS16(w0,          bd0);
    GL_LDS16(w0 + 2048,   bd0 + 2048);
    GL_LDS16(w0 + 32768,  bd0 + 4096);
    GL_LDS16(w0 + 34816,  bd0 + 6144);
    const int ko = it * 64;
#define ASTAGE(XS, AW) { f32x4 u = *(const f32x4*)((XS) + ko); f32x4 v = *(const f32x4*)((XS) + ko + 4); \
    u16x8 h;                                                                              \
    h[0] = cvtbf(u[0]); h[1] = cvtbf(u[1]); h[2] = cvtbf(u[2]); h[3] = cvtbf(u[3]);       \
    h[4] = cvtbf(v[0]); h[5] = cvtbf(v[1]); h[6] = cvtbf(v[2]); h[7] = cvtbf(v[3]);       \
    *(u16x8*)((char*)As + (AW)) = h; }
    ASTAGE(xs0, aw0) ASTAGE(xs1, aw1) ASTAGE(xs2, aw2) ASTAGE(xs3, aw3)
#undef ASTAGE
    __syncthreads();
#pragma unroll
    for (int kt2 = 0; kt2 < 2; ++kt2) {
      s16x8 af[4], bfr[4];
#pragma unroll
      for (int m = 0; m < 4; ++m) af[m] = *(const s16x8*)(Ab + ((kt2 * 8 + wr * 4 + m) << 10));
#pragma unroll
      for (int n = 0; n < 4; ++n) bfr[n] = *(const s16x8*)(Bb + ((kt2 * 8 + wc * 4 + n) << 10));
#pragma unroll
      for (int m = 0; m < 4; ++m)
#pragma unroll
        for (int n = 0; n < 4; ++n)
          acc[m][n] = __builtin_amdgcn_mfma_f32_16x16x32_bf16(af[m], bfr[n], acc[m][n], 0, 0, 0);
    }
    __syncthreads();
  }

  const long orow0 = m0 + wr * 64 + (lane >> 4) * 4;
  const int  ocol0 = n0 + wc * 64 + (lane & 15);
#pragma unroll
  for (int n = 0; n < 4; ++n) {
    const int cc = ocol0 + n * 16;
    const float bb = bvec[cc];
#pragma unroll
    for (int m = 0; m < 4; ++m) {
      const long r = orow0 + m * 16;
#pragma unroll
      for (int q = 0; q < 4; ++q)
        out[(r + q) * 1024 + cc] = acc[m][n][q] + bb;
    }
  }
}

extern "C" void kernel_launch(void* const* d_in, const int* in_sizes, int n_in,
                              void* d_out, int out_size, void* d_ws, size_t ws_size,
                              hipStream_t stream) {
  const float* x  = (const float*)d_in[0];
  const float* A  = (const float*)d_in[1];
  const float* bv = (const float*)d_in[2];
  float* out = (float*)d_out;
  char* ws = (char*)d_ws;

  float* B   = (float*)(ws);                              // 4 MB, becomes Y
  float* Y   = B;
  float* M   = (float*)(ws + (4u << 20));                 // 4 MB
  u16*   Wf  = (u16*)  (ws + (8u << 20));                 // 2 MB
  float* rd2 = (float*)(ws + (10u << 20));                // 4 KB
  float* U   = (float*)(ws + (10u << 20) + 65536);        // 1 MB
  u16*   Xbf = (u16*)  (ws + (12u << 20));                // 128 MB

  hipMemsetAsync(M, 0, 1024 * 1024 * sizeof(float), stream);
  k_bbt<<<dim3(16, 16), 256, 0, stream>>>(A, B);
  k_tinv<<<20, 256, 0, stream>>>(B, M, rd2);
  for (int lvl = 0; lvl < 4; ++lvl) {
    const int nt2 = 1 << (2 * lvl);
    const int np  = 8 >> lvl;
    k_u<<<dim3(nt2, np), 256, 0, stream>>>(B, rd2, M, U, lvl);
    k_moff<<<dim3(nt2, np), 256, 0, stream>>>(M, U, lvl);
  }
  k_yma<<<dim3(16, 16), 256, 0, stream>>>(M, A, Y);
  k_w<<<dim3(16, 16), 256, 0, stream>>>(A, Y, rd2, Wf);

  const size_t need = (12u << 20) + (size_t)65536 * 1024 * 2;
  if (ws_size >= need) {
    k_xbf<<<2048, 256, 0, stream>>>(x, Xbf);
    k_out8<<<1024, 512, 0, stream>>>(Xbf, Wf, bv, out);
  } else {
    k_out_r<<<4096, 256, 0, stream>>>(x, Wf, bv, out);
  }
}

// Round 7
// 564.467 us; speedup vs baseline: 1.0195x; 1.0195x over previous
//
#include <hip/hip_runtime.h>
#include <hip/hip_bf16.h>

typedef unsigned short u16;
typedef float f32x4 __attribute__((ext_vector_type(4)));
typedef u16   u16x8 __attribute__((ext_vector_type(8)));
typedef u16   u16x4 __attribute__((ext_vector_type(4)));
typedef short s16x8 __attribute__((ext_vector_type(8)));

__device__ __forceinline__ u16 f2bf(float f) {
  unsigned u = __builtin_bit_cast(unsigned, f);
  unsigned r = (u + 0x7fffu + ((u >> 16) & 1u)) >> 16;
  return (u16)r;
}
__device__ __forceinline__ u16 cvtbf(float f) {
  return __builtin_bit_cast(u16, __float2bfloat16(f));
}

#define GL_LDS16(gp, lp)                                                     \
  __builtin_amdgcn_global_load_lds((const __attribute__((address_space(1))) void*)(gp), \
                                   (__attribute__((address_space(3))) void*)(lp), 16, 0, 0)

// ================= B = A*A^T (256 blocks) + rd2 on diag + Xbf conversion (2048 extra blocks) =================
__global__ __launch_bounds__(256) void k_bbtx(const float* __restrict__ A, float* __restrict__ B,
                                              float* __restrict__ rd2,
                                              const float* __restrict__ X, u16* __restrict__ Xbf) {
  const int bid = blockIdx.x;
  const int tid = threadIdx.x;
  if (bid >= 256) {
    // ---- X fp32 -> bf16 in A-fragment order: [mi256][it(16)][kt2(2)][msub(16)][lane(64)][8]
    const int vb = bid - 256;
    for (int gid = vb * 256 + tid; gid < (1 << 23); gid += 2048 * 256) {
      const int mi   = gid >> 15;
      const int it   = (gid >> 11) & 15;
      const int kt2  = (gid >> 10) & 1;
      const int msub = (gid >> 6) & 15;
      const int lane = gid & 63;
      const int m = mi * 256 + msub * 16 + (lane & 15);
      const int k = it * 64 + kt2 * 32 + (lane >> 4) * 8;
      const float* s = X + (size_t)m * 1024 + k;
      f32x4 u = *(const f32x4*)s;
      f32x4 v = *(const f32x4*)(s + 4);
      u16x8 h;
      h[0] = cvtbf(u[0]); h[1] = cvtbf(u[1]); h[2] = cvtbf(u[2]); h[3] = cvtbf(u[3]);
      h[4] = cvtbf(v[0]); h[5] = cvtbf(v[1]); h[6] = cvtbf(v[2]); h[7] = cvtbf(v[3]);
      *(u16x8*)(Xbf + (size_t)gid * 8) = h;
    }
    return;
  }
  // ---- B = A * A^T, 64x64 tile
  __shared__ float s0[32][68];
  __shared__ float s1[32][68];
  const int i0 = (bid >> 4) * 64, j0 = (bid & 15) * 64;
  const int tx = tid & 15, ty = tid >> 4;
  const int sr = tid >> 2, sc = (tid & 3) * 8;
  f32x4 acc[4];
#pragma unroll
  for (int q = 0; q < 4; ++q) acc[q] = {0.f, 0.f, 0.f, 0.f};

  for (int k0 = 0; k0 < 1024; k0 += 32) {
    f32x4 a0 = *(const f32x4*)&A[(size_t)(i0 + sr) * 1024 + k0 + sc];
    f32x4 a1 = *(const f32x4*)&A[(size_t)(i0 + sr) * 1024 + k0 + sc + 4];
    f32x4 b0 = *(const f32x4*)&A[(size_t)(j0 + sr) * 1024 + k0 + sc];
    f32x4 b1 = *(const f32x4*)&A[(size_t)(j0 + sr) * 1024 + k0 + sc + 4];
    __syncthreads();
#pragma unroll
    for (int q = 0; q < 4; ++q) {
      s0[sc + q][sr] = a0[q]; s0[sc + 4 + q][sr] = a1[q];
      s1[sc + q][sr] = b0[q]; s1[sc + 4 + q][sr] = b1[q];
    }
    __syncthreads();
#pragma unroll
    for (int kk = 0; kk < 32; ++kk) {
      f32x4 av = *(const f32x4*)&s0[kk][ty * 4];
      f32x4 bv = *(const f32x4*)&s1[kk][tx * 4];
#pragma unroll
      for (int q = 0; q < 4; ++q) acc[q] += bv * av[q];
    }
  }
#pragma unroll
  for (int q = 0; q < 4; ++q)
    *(f32x4*)&B[(size_t)(i0 + ty * 4 + q) * 1024 + j0 + tx * 4] = acc[q];
  if (i0 == j0 && tx == ty) {
#pragma unroll
    for (int q = 0; q < 4; ++q) rd2[i0 + ty * 4 + q] = 2.0f / acc[q][q];
  }
}

// ================= diag-block inverses T_k -> M diagonal =================
__global__ __launch_bounds__(256) void k_tinv(const float* __restrict__ B, const float* __restrict__ rd2,
                                              float* __restrict__ M) {
  __shared__ float Ct[64][68];
  __shared__ float rdl[64];
  const int tid = threadIdx.x;
  const int k0 = blockIdx.x * 64;
  if (tid < 64) rdl[tid] = rd2[k0 + tid];
  __syncthreads();
  {
    const int i = tid >> 2, j0q = (tid & 3) * 16;
#pragma unroll
    for (int jj = 0; jj < 16; ++jj) {
      int j = j0q + jj;
      Ct[i][j] = (j > i) ? B[(size_t)(k0 + i) * 1024 + k0 + j] * rdl[j] : 0.0f;
    }
  }
  __syncthreads();
  if (tid < 64) {
    float pc[64];
#pragma unroll
    for (int r = 0; r < 64; ++r) pc[r] = (r == tid) ? 1.0f : 0.0f;
#pragma unroll
    for (int i = 0; i < 63; ++i) {
      const float pi = pc[i];
#pragma unroll
      for (int j = i + 1; j < 64; ++j) pc[j] -= Ct[i][j] * pi;
    }
#pragma unroll
    for (int r = 0; r < 64; ++r) M[(size_t)(k0 + r) * 1024 + k0 + tid] = pc[r];
  }
}

// ================= level GEMM 1: U_p = Cscaled[a+s:a+2s, a:a+s] * M[a:a+s, a:a+s] =================
__global__ __launch_bounds__(256) void k_u(const float* __restrict__ B, const float* __restrict__ rd2,
                                           const float* __restrict__ M, float* __restrict__ U, int lvl) {
  __shared__ float sA[32][68];
  __shared__ float sB[32][68];
  const int tid = threadIdx.x;
  const int s = 64 << lvl;
  const int ti = blockIdx.x >> lvl, tj = blockIdx.x & ((1 << lvl) - 1);
  const int a = blockIdx.y * (s << 1);
  const int m0 = a + s + ti * 64;
  const int n0 = a + tj * 64;
  const int tx = tid & 15, ty = tid >> 4;
  const int asr = tid >> 2, asc = (tid & 3) * 8;
  const int bkr = tid >> 3, bnc = (tid & 7) * 8;
  const float r2 = rd2[m0 + asr];
  f32x4 acc[4];
#pragma unroll
  for (int q = 0; q < 4; ++q) acc[q] = {0.f, 0.f, 0.f, 0.f};

  for (int k0 = 0; k0 < s; k0 += 32) {
    f32x4 a0 = *(const f32x4*)&B[(size_t)(m0 + asr) * 1024 + a + k0 + asc];
    f32x4 a1 = *(const f32x4*)&B[(size_t)(m0 + asr) * 1024 + a + k0 + asc + 4];
    f32x4 b0 = *(const f32x4*)&M[(size_t)(a + k0 + bkr) * 1024 + n0 + bnc];
    f32x4 b1 = *(const f32x4*)&M[(size_t)(a + k0 + bkr) * 1024 + n0 + bnc + 4];
    a0 *= r2; a1 *= r2;
    __syncthreads();
#pragma unroll
    for (int q = 0; q < 4; ++q) { sA[asc + q][asr] = a0[q]; sA[asc + 4 + q][asr] = a1[q]; }
    *(f32x4*)&sB[bkr][bnc] = b0;
    *(f32x4*)&sB[bkr][bnc + 4] = b1;
    __syncthreads();
#pragma unroll
    for (int kk = 0; kk < 32; ++kk) {
      f32x4 av = *(const f32x4*)&sA[kk][ty * 4];
      f32x4 bv = *(const f32x4*)&sB[kk][tx * 4];
#pragma unroll
      for (int q = 0; q < 4; ++q) acc[q] += bv * av[q];
    }
  }
  float* up = U + (size_t)blockIdx.y * s * s;
#pragma unroll
  for (int q = 0; q < 4; ++q)
    *(f32x4*)&up[(size_t)(ti * 64 + ty * 4 + q) * s + tj * 64 + tx * 4] = acc[q];
}

// ================= level GEMM 2: M[a+s:a+2s, a:a+s] = - M[a+s:a+2s, a+s:a+2s] * U_p =================
__global__ __launch_bounds__(256) void k_moff(float* __restrict__ M, const float* __restrict__ U, int lvl) {
  __shared__ float sA[32][68];
  __shared__ float sB[32][68];
  const int tid = threadIdx.x;
  const int s = 64 << lvl;
  const int ti = blockIdx.x >> lvl, tj = blockIdx.x & ((1 << lvl) - 1);
  const int a = blockIdx.y * (s << 1);
  const int m0 = a + s + ti * 64;
  const int n0 = a + tj * 64;
  const int tx = tid & 15, ty = tid >> 4;
  const int asr = tid >> 2, asc = (tid & 3) * 8;
  const int bkr = tid >> 3, bnc = (tid & 7) * 8;
  const float* up = U + (size_t)blockIdx.y * s * s;
  f32x4 acc[4];
#pragma unroll
  for (int q = 0; q < 4; ++q) acc[q] = {0.f, 0.f, 0.f, 0.f};

  for (int k0 = 0; k0 < s; k0 += 32) {
    f32x4 a0 = *(const f32x4*)&M[(size_t)(m0 + asr) * 1024 + a + s + k0 + asc];
    f32x4 a1 = *(const f32x4*)&M[(size_t)(m0 + asr) * 1024 + a + s + k0 + asc + 4];
    f32x4 b0 = *(const f32x4*)&up[(size_t)(k0 + bkr) * s + tj * 64 + bnc];
    f32x4 b1 = *(const f32x4*)&up[(size_t)(k0 + bkr) * s + tj * 64 + bnc + 4];
    __syncthreads();
#pragma unroll
    for (int q = 0; q < 4; ++q) { sA[asc + q][asr] = a0[q]; sA[asc + 4 + q][asr] = a1[q]; }
    *(f32x4*)&sB[bkr][bnc] = b0;
    *(f32x4*)&sB[bkr][bnc + 4] = b1;
    __syncthreads();
#pragma unroll
    for (int kk = 0; kk < 32; ++kk) {
      f32x4 av = *(const f32x4*)&sA[kk][ty * 4];
      f32x4 bv = *(const f32x4*)&sB[kk][tx * 4];
#pragma unroll
      for (int q = 0; q < 4; ++q) acc[q] += bv * av[q];
    }
  }
#pragma unroll
  for (int q = 0; q < 4; ++q)
    *(f32x4*)&M[(size_t)(m0 + ty * 4 + q) * 1024 + n0 + tx * 4] = -acc[q];
}

// ================= Y = M * A (triangular K-skip) =================
__global__ __launch_bounds__(256) void k_yma(const float* __restrict__ M, const float* __restrict__ A,
                                             float* __restrict__ Y) {
  __shared__ float sA[32][68];
  __shared__ float sB[32][68];
  const int tid = threadIdx.x;
  const int ri = blockIdx.y, cj = blockIdx.x;
  const int m0 = ri * 64, n0 = cj * 64;
  const int kmax = (ri + 1) * 64;
  const int tx = tid & 15, ty = tid >> 4;
  const int asr = tid >> 2, asc = (tid & 3) * 8;
  const int bkr = tid >> 3, bnc = (tid & 7) * 8;
  f32x4 acc[4];
#pragma unroll
  for (int q = 0; q < 4; ++q) acc[q] = {0.f, 0.f, 0.f, 0.f};

  for (int k0 = 0; k0 < kmax; k0 += 32) {
    f32x4 a0 = *(const f32x4*)&M[(size_t)(m0 + asr) * 1024 + k0 + asc];
    f32x4 a1 = *(const f32x4*)&M[(size_t)(m0 + asr) * 1024 + k0 + asc + 4];
    f32x4 b0 = *(const f32x4*)&A[(size_t)(k0 + bkr) * 1024 + n0 + bnc];
    f32x4 b1 = *(const f32x4*)&A[(size_t)(k0 + bkr) * 1024 + n0 + bnc + 4];
    __syncthreads();
#pragma unroll
    for (int q = 0; q < 4; ++q) { sA[asc + q][asr] = a0[q]; sA[asc + 4 + q][asr] = a1[q]; }
    *(f32x4*)&sB[bkr][bnc] = b0;
    *(f32x4*)&sB[bkr][bnc + 4] = b1;
    __syncthreads();
#pragma unroll
    for (int kk = 0; kk < 32; ++kk) {
      f32x4 av = *(const f32x4*)&sA[kk][ty * 4];
      f32x4 bv = *(const f32x4*)&sB[kk][tx * 4];
#pragma unroll
      for (int q = 0; q < 4; ++q) acc[q] += bv * av[q];
    }
  }
#pragma unroll
  for (int q = 0; q < 4; ++q)
    *(f32x4*)&Y[(size_t)(m0 + ty * 4 + q) * 1024 + n0 + tx * 4] = acc[q];
}

// ================= Wf in MFMA-B-fragment order =================
__global__ __launch_bounds__(256) void k_w(const float* __restrict__ A, const float* __restrict__ P,
                                           const float* __restrict__ rd2, u16* __restrict__ Wf) {
  __shared__ float As[32][68];
  __shared__ float Ps[32][68];
  const int tid = threadIdx.x;
  const int kb = blockIdx.y * 64, nb = blockIdx.x * 64;
  const int sr = tid >> 3, sc = (tid & 7) * 8;
  const int tx = tid & 15, ty = tid >> 4;
  f32x4 acc[4];
#pragma unroll
  for (int q = 0; q < 4; ++q) acc[q] = {0.f, 0.f, 0.f, 0.f};

  for (int i0 = 0; i0 < 1024; i0 += 32) {
    float r2 = rd2[i0 + sr];
    f32x4 a0 = *(const f32x4*)&A[(size_t)(i0 + sr) * 1024 + kb + sc];
    f32x4 a1 = *(const f32x4*)&A[(size_t)(i0 + sr) * 1024 + kb + sc + 4];
    f32x4 p0 = *(const f32x4*)&P[(size_t)(i0 + sr) * 1024 + nb + sc];
    f32x4 p1 = *(const f32x4*)&P[(size_t)(i0 + sr) * 1024 + nb + sc + 4];
    __syncthreads();
    *(f32x4*)&As[sr][sc]     = a0 * r2;
    *(f32x4*)&As[sr][sc + 4] = a1 * r2;
    *(f32x4*)&Ps[sr][sc]     = p0;
    *(f32x4*)&Ps[sr][sc + 4] = p1;
    __syncthreads();
#pragma unroll
    for (int i = 0; i < 32; ++i) {
      f32x4 av = *(const f32x4*)&As[i][ty * 4];
      f32x4 pv = *(const f32x4*)&Ps[i][tx * 4];
#pragma unroll
      for (int q = 0; q < 4; ++q) acc[q] += pv * av[q];
    }
  }
  const int ktile = (kb + ty * 4) >> 5;
  const int kg = ((ty * 4) >> 3) & 3;
  const int e0 = (ty * 4) & 7;
#pragma unroll
  for (int j = 0; j < 4; ++j) {
    int n = nb + tx * 4 + j;
    int nt = n >> 4;
    int ln = kg * 16 + (n & 15);
    u16x4 pk;
#pragma unroll
    for (int q = 0; q < 4; ++q) {
      int kk = kb + ty * 4 + q;
      float w = ((kk == n) ? 1.0f : 0.0f) - acc[q][j];
      pk[q] = f2bf(w);
    }
    *(u16x4*)&Wf[((size_t)(ktile * 64 + nt) * 64 + ln) * 8 + e0] = pk;
  }
}

// ================= 256x256 GEMM, counted-vmcnt + register-double-buffered fragments =================
// 8 waves (2M x 4N). Unit = BK=32 half (8KB A + 8KB B = 4 loads). 4 LDS slots, prefetch depth 3.
// Phase I: vmcnt(4) [half I+1 landed] -> barrier -> gload I+3 -> ds_read I+1 -> regNext -> MFMA(regCur).
template<int I>
__device__ __forceinline__ void phase_body(const u16* __restrict__ ax, const u16* __restrict__ wbase,
                                           u16* As, u16* Bs, int tid, int wr, int wc, int lane,
                                           f32x4 (&acc)[8][4],
                                           s16x8 (&afA)[8], s16x8 (&bfA)[4],
                                           s16x8 (&afB)[8], s16x8 (&bfB)[4]) {
  s16x8 (&afC)[8] = ((I & 1) == 0) ? afA : afB;   // current half's fragments
  s16x8 (&bfC)[4] = ((I & 1) == 0) ? bfA : bfB;
  s16x8 (&afN)[8] = ((I & 1) == 0) ? afB : afA;   // next half's fragments
  s16x8 (&bfN)[4] = ((I & 1) == 0) ? bfB : bfA;

  if constexpr (I <= 29)      asm volatile("s_waitcnt vmcnt(4)" ::: "memory");
  else if constexpr (I == 30) asm volatile("s_waitcnt vmcnt(0)" ::: "memory");
  if constexpr (I <= 30) __builtin_amdgcn_s_barrier();

  if constexpr (I + 3 < 32) {   // prefetch half I+3 into slot (I+3)&3 (reads of it finished phase I-1)
    constexpr int j = I + 3, jt = j >> 1, jk = j & 1, js = j & 3;
    GL_LDS16(ax + (size_t)jt * 16384 + jk * 8192 + tid * 8,            As + js * 8192 + tid * 8);
    GL_LDS16(ax + (size_t)jt * 16384 + jk * 8192 + 4096 + tid * 8,     As + js * 8192 + 4096 + tid * 8);
    GL_LDS16(wbase + (size_t)jt * 65536 + jk * 32768 + tid * 8,        Bs + js * 8192 + tid * 8);
    GL_LDS16(wbase + (size_t)jt * 65536 + jk * 32768 + 4096 + tid * 8, Bs + js * 8192 + 4096 + tid * 8);
  }
  if constexpr (I + 1 < 32) {   // ds_read half I+1 -> regNext (completes under the MFMA block below)
    constexpr int js = (I + 1) & 3;
    const u16* Asb = As + js * 8192;
    const u16* Bsb = Bs + js * 8192;
#pragma unroll
    for (int m = 0; m < 8; ++m) afN[m] = *(const s16x8*)&Asb[(wr * 8 + m) * 512 + lane * 8];
#pragma unroll
    for (int n = 0; n < 4; ++n) bfN[n] = *(const s16x8*)&Bsb[(wc * 4 + n) * 512 + lane * 8];
  }
  __builtin_amdgcn_s_setprio(1);
#pragma unroll
  for (int m = 0; m < 8; ++m)
#pragma unroll
    for (int n = 0; n < 4; ++n)
      acc[m][n] = __builtin_amdgcn_mfma_f32_16x16x32_bf16(afC[m], bfC[n], acc[m][n], 0, 0, 0);
  __builtin_amdgcn_s_setprio(0);
}

__global__ __launch_bounds__(512, 2) void k_out8(const u16* __restrict__ Xbf, const u16* __restrict__ Wf,
                                                 const float* __restrict__ bvec, float* __restrict__ out) {
  __shared__ u16 As[32768];   // 4 slots x [msub(16)][lane(64)][8]  (64 KiB)
  __shared__ u16 Bs[32768];
  const int tid = threadIdx.x;
  const int lane = tid & 63, wid = tid >> 6;
  const int wr = wid >> 2, wc = wid & 3;          // 2M x 4N waves; per-wave out 128x64
  const int lin = blockIdx.x;
  const int xcd = lin & 7, idx = lin >> 3;
  const int mi = xcd * 32 + (idx >> 2);           // XCD-chunked
  const int ni = idx & 3;

  const u16* ax = Xbf + (size_t)mi * 262144;
  const u16* wbase = Wf + (size_t)ni * 8192;

  f32x4 acc[8][4];
#pragma unroll
  for (int m = 0; m < 8; ++m)
#pragma unroll
    for (int n = 0; n < 4; ++n) acc[m][n] = {0.f, 0.f, 0.f, 0.f};

  // prologue: issue halves 0,1,2 (12 loads); wait half 0; read its fragments
#pragma unroll
  for (int j = 0; j < 3; ++j) {
    const int jt = j >> 1, jk = j & 1;
    GL_LDS16(ax + (size_t)jt * 16384 + jk * 8192 + tid * 8,            As + j * 8192 + tid * 8);
    GL_LDS16(ax + (size_t)jt * 16384 + jk * 8192 + 4096 + tid * 8,     As + j * 8192 + 4096 + tid * 8);
    GL_LDS16(wbase + (size_t)jt * 65536 + jk * 32768 + tid * 8,        Bs + j * 8192 + tid * 8);
    GL_LDS16(wbase + (size_t)jt * 65536 + jk * 32768 + 4096 + tid * 8, Bs + j * 8192 + 4096 + tid * 8);
  }
  asm volatile("s_waitcnt vmcnt(8)" ::: "memory");
  __builtin_amdgcn_s_barrier();

  s16x8 afA[8], bfA[4], afB[8], bfB[4];
#pragma unroll
  for (int m = 0; m < 8; ++m) afA[m] = *(const s16x8*)&As[(wr * 8 + m) * 512 + lane * 8];
#pragma unroll
  for (int n = 0; n < 4; ++n) bfA[n] = *(const s16x8*)&Bs[(wc * 4 + n) * 512 + lane * 8];

#define PH(I) phase_body<I>(ax, wbase, As, Bs, tid, wr, wc, lane, acc, afA, bfA, afB, bfB);
  PH(0)  PH(1)  PH(2)  PH(3)  PH(4)  PH(5)  PH(6)  PH(7)
  PH(8)  PH(9)  PH(10) PH(11) PH(12) PH(13) PH(14) PH(15)
  PH(16) PH(17) PH(18) PH(19) PH(20) PH(21) PH(22) PH(23)
  PH(24) PH(25) PH(26) PH(27) PH(28) PH(29) PH(30) PH(31)
#undef PH

  const long orow0 = (long)mi * 256 + wr * 128 + (lane >> 4) * 4;
  const int  ocol0 = ni * 256 + wc * 64 + (lane & 15);
#pragma unroll
  for (int aj = 0; aj < 4; ++aj) {
    const int cc = ocol0 + aj * 16;
    const float bb = bvec[cc];
#pragma unroll
    for (int ai = 0; ai < 8; ++ai) {
      const long r = orow0 + ai * 16;
#pragma unroll
      for (int q = 0; q < 4; ++q)
        out[(r + q) * 1024 + cc] = acc[ai][aj][q] + bb;
    }
  }
}

// ================= fallback GEMM (reg-staged A) if workspace too small for Xbf =================
__global__ __launch_bounds__(256) void k_out_r(const float* __restrict__ X, const u16* __restrict__ Wf,
                                               const float* __restrict__ bvec, float* __restrict__ out) {
  __shared__ u16 As[8192];
  __shared__ u16 Bs[8192];
  const int tid = threadIdx.x;
  const int lane = tid & 63, wid = tid >> 6;
  const int wr = wid >> 1, wc = wid & 1;
  const int lin = blockIdx.x;
  const int mi = (lin & 7) * 64 + (lin >> 6);
  const int ni = (lin >> 3) & 7;
  const long m0 = (long)mi * 128;
  const int n0 = ni * 128;

  const float *xs0, *xs1, *xs2, *xs3;
  int aw0, aw1, aw2, aw3;
#define APREP(J, XS, AW) { int c = (J) * 256 + tid; int m = c >> 3, kg8 = c & 7;       \
    XS = X + (m0 + m) * 1024 + kg8 * 8;                                                \
    int kt2 = kg8 >> 2, ks = kg8 & 3, msub = m >> 4, mm = m & 15;                      \
    AW = (((kt2 * 8 + msub) * 64 + ks * 16 + mm) * 16) ^ (ks << 4); }
  APREP(0, xs0, aw0) APREP(1, xs1, aw1) APREP(2, xs2, aw2) APREP(3, xs3, aw3)
#undef APREP

  const u16* wsrc0 = Wf + (size_t)ni * 4096 + tid * 8;
  u16* bd0 = Bs + tid * 8;
  const int aro = (lane * 16) ^ (((lane >> 4) & 3) << 4);
  const char* Ab = (const char*)As + aro;
  const char* Bb = (const char*)Bs + lane * 16;

  f32x4 acc[4][4];
#pragma unroll
  for (int m = 0; m < 4; ++m)
#pragma unroll
    for (int n = 0; n < 4; ++n) acc[m][n] = {0.f, 0.f, 0.f, 0.f};

  for (int it = 0; it < 16; ++it) {
    const u16* w0 = wsrc0 + (size_t)it * 65536;
    GL_LDS16(w0,          bd0);
    GL_LDS16(w0 + 2048,   bd0 + 2048);
    GL_LDS16(w0 + 32768,  bd0 + 4096);
    GL_LDS16(w0 + 34816,  bd0 + 6144);
    const int ko = it * 64;
#define ASTAGE(XS, AW) { f32x4 u = *(const f32x4*)((XS) + ko); f32x4 v = *(const f32x4*)((XS) + ko + 4); \
    u16x8 h;                                                                              \
    h[0] = cvtbf(u[0]); h[1] = cvtbf(u[1]); h[2] = cvtbf(u[2]); h[3] = cvtbf(u[3]);       \
    h[4] = cvtbf(v[0]); h[5] = cvtbf(v[1]); h[6] = cvtbf(v[2]); h[7] = cvtbf(v[3]);       \
    *(u16x8*)((char*)As + (AW)) = h; }
    ASTAGE(xs0, aw0) ASTAGE(xs1, aw1) ASTAGE(xs2, aw2) ASTAGE(xs3, aw3)
#undef ASTAGE
    __syncthreads();
#pragma unroll
    for (int kt2 = 0; kt2 < 2; ++kt2) {
      s16x8 af[4], bfr[4];
#pragma unroll
      for (int m = 0; m < 4; ++m) af[m] = *(const s16x8*)(Ab + ((kt2 * 8 + wr * 4 + m) << 10));
#pragma unroll
      for (int n = 0; n < 4; ++n) bfr[n] = *(const s16x8*)(Bb + ((kt2 * 8 + wc * 4 + n) << 10));
#pragma unroll
      for (int m = 0; m < 4; ++m)
#pragma unroll
        for (int n = 0; n < 4; ++n)
          acc[m][n] = __builtin_amdgcn_mfma_f32_16x16x32_bf16(af[m], bfr[n], acc[m][n], 0, 0, 0);
    }
    __syncthreads();
  }

  const long orow0 = m0 + wr * 64 + (lane >> 4) * 4;
  const int  ocol0 = n0 + wc * 64 + (lane & 15);
#pragma unroll
  for (int n = 0; n < 4; ++n) {
    const int cc = ocol0 + n * 16;
    const float bb = bvec[cc];
#pragma unroll
    for (int m = 0; m < 4; ++m) {
      const long r = orow0 + m * 16;
#pragma unroll
      for (int q = 0; q < 4; ++q)
        out[(r + q) * 1024 + cc] = acc[m][n][q] + bb;
    }
  }
}

extern "C" void kernel_launch(void* const* d_in, const int* in_sizes, int n_in,
                              void* d_out, int out_size, void* d_ws, size_t ws_size,
                              hipStream_t stream) {
  const float* x  = (const float*)d_in[0];
  const float* A  = (const float*)d_in[1];
  const float* bv = (const float*)d_in[2];
  float* out = (float*)d_out;
  char* ws = (char*)d_ws;

  float* B   = (float*)(ws);                              // 4 MB, becomes Y
  float* Y   = B;
  float* M   = (float*)(ws + (4u << 20));                 // 4 MB
  u16*   Wf  = (u16*)  (ws + (8u << 20));                 // 2 MB
  float* rd2 = (float*)(ws + (10u << 20));                // 4 KB
  float* U   = (float*)(ws + (10u << 20) + 65536);        // 1 MB
  u16*   Xbf = (u16*)  (ws + (12u << 20));                // 128 MB

  const size_t need = (12u << 20) + (size_t)65536 * 1024 * 2;
  const bool big = (ws_size >= need);

  hipMemsetAsync(M, 0, 1024 * 1024 * sizeof(float), stream);
  k_bbtx<<<big ? 2304 : 256, 256, 0, stream>>>(A, B, rd2, x, Xbf);   // BBT + rd2 (+ Xbf convert)
  k_tinv<<<16, 256, 0, stream>>>(B, rd2, M);
  for (int lvl = 0; lvl < 4; ++lvl) {
    const int nt2 = 1 << (2 * lvl);
    const int np  = 8 >> lvl;
    k_u<<<dim3(nt2, np), 256, 0, stream>>>(B, rd2, M, U, lvl);
    k_moff<<<dim3(nt2, np), 256, 0, stream>>>(M, U, lvl);
  }
  k_yma<<<dim3(16, 16), 256, 0, stream>>>(M, A, Y);
  k_w<<<dim3(16, 16), 256, 0, stream>>>(A, Y, rd2, Wf);

  if (big) {
    k_out8<<<1024, 512, 0, stream>>>(Xbf, Wf, bv, out);
  } else {
    k_out_r<<<4096, 256, 0, stream>>>(x, Wf, bv, out);
  }
}